// Round 3
// baseline (506.543 us; speedup 1.0000x reference)
//
#include <hip/hip_runtime.h>
#include <stdint.h>

#define TT 300
#define DD 40
#define AROW 200      // halfwords per A row (100 words -> +4 bank skew/row)
#define ZROW 260      // words per zbuf row

typedef __attribute__((ext_vector_type(8))) short short8;
typedef __attribute__((ext_vector_type(4))) float f32x4;

// One LDS object; regions alias on purpose:
//  - wstage is clobbered after init (forces B-fragments to stay in registers)
//  - head-phase buffers reuse the recurrence buffers after the time loop
union SMemU {
  ushort wstage[64 * 128];                 // 16384 B (init only)
  struct {
    ushort Abuf[2][16 * AROW];             // 2 x 6400 B (double-buffered A)
    float  zbuf[4 * ZROW];                 // 4160 B (wave-private z slices)
  } s;
  struct {
    float lg[4 * 512];                     // 8192 B logits
    float d1t[128 * 4];                    // 2048 B dense1 out, [k][s]
    float hbuf[4 * 64];                    // 1024 B final h
  } h;
};

__device__ __forceinline__ ushort f2bf(float f) {
  uint32_t b = __float_as_uint(f);
  b += 0x7FFFu + ((b >> 16) & 1u);   // RNE
  return (ushort)(b >> 16);
}
__device__ __forceinline__ float bf2f(ushort h) {
  return __uint_as_float((uint32_t)h << 16);
}
__device__ __forceinline__ float sigm(float x) {
  return __builtin_amdgcn_rcpf(1.0f + __expf(-x));
}
__device__ __forceinline__ float tanh_f(float x) {
  return 1.0f - 2.0f * __builtin_amdgcn_rcpf(1.0f + __expf(2.0f * x));
}
// barrier WITHOUT vmcnt drain: keeps the x-prefetch loads in flight
__device__ __forceinline__ void block_sync_lds() {
  asm volatile("s_waitcnt lgkmcnt(0)" ::: "memory");
  __builtin_amdgcn_s_barrier();
}

// K layout (192 = 6 ktiles of 32):
//   k 0..39: x_t | 40..63: zero pad | 64..127: h_hi (bf16) | 128..191: h_lo
// Weight cols permuted: col = u*4 + g (u=unit, g=gate i,j,f,o);
// wave w owns cols 64w..64w+63 <=> units 16w..16w+15 (gate quads wave-local).
__global__ __launch_bounds__(256, 2) void lstm_fused_kernel(
    const float* __restrict__ X, const int* __restrict__ seqlen,
    const float* __restrict__ Wk, const float* __restrict__ bias,
    const float* __restrict__ W1, const float* __restrict__ b1,
    const float* __restrict__ gamma, const float* __restrict__ beta,
    const float* __restrict__ mmean, const float* __restrict__ mvar,
    const float* __restrict__ W2, const float* __restrict__ b2,
    float* __restrict__ out)
{
  __shared__ SMemU sm;
  const int tid = threadIdx.x;
  const int wv = tid >> 6, lane = tid & 63;
  const int s0 = blockIdx.x * 4;

  // ---- B fragments -> registers (24 frags = 96 regs/wave) ----
  short8 Bf[6][4];
  for (int c = 0; c < 4; ++c) {
    __syncthreads();
    for (int i = tid; i < 64 * 128; i += 256) {   // cc = col-in-slice, kp = padded k
      int cc = i >> 7, kp = i & 127;
      ushort v = 0;
      int ks = (kp < 40) ? kp : ((kp >= 64) ? (kp - 24) : -1);
      if (ks >= 0) {
        int u = c * 16 + (cc >> 2), g = cc & 3;
        v = f2bf(Wk[ks * 256 + g * 64 + u]);
      }
      sm.wstage[cc * 128 + kp] = v;
    }
    __syncthreads();
    if (wv == c) {
      #pragma unroll
      for (int kt = 0; kt < 6; ++kt) {
        int kk = ((kt < 4) ? kt * 32 : (kt * 32 - 64)) + (lane >> 4) * 8;
        #pragma unroll
        for (int nt = 0; nt < 4; ++nt)
          Bf[kt][nt] = *reinterpret_cast<const short8*>(
              &sm.wstage[(nt * 16 + (lane & 15)) * 128 + kk]);
      }
    }
  }
  __syncthreads();

  // ---- zero A buffers (clobbers wstage -> Bf must stay in registers) ----
  {
    uint32_t* az = reinterpret_cast<uint32_t*>(&sm.s.Abuf[0][0]);
    for (int i = tid; i < 2 * 16 * AROW / 2; i += 256) az[i] = 0;
  }
  __syncthreads();

  // ---- per-lane assignment: one (sample, unit) pair ----
  const int ps = lane >> 4;                 // sample 0..3
  const int u  = wv * 16 + (lane & 15);     // unit (wave-local)
  const int mylen = seqlen[s0 + ps];
  const float bi = bias[u], bj = bias[64 + u];
  const float bfp = bias[128 + u] + 1.0f, bo = bias[192 + u];

  int ml = seqlen[s0 + (lane & 3)];
  #pragma unroll
  for (int off = 1; off < 64; off <<= 1) ml = max(ml, __shfl_xor(ml, off));
  ml = __builtin_amdgcn_readfirstlane(ml);

  // x loader threads: 160 = 4 samples x 40 dims
  const int sA = (tid * 205) >> 13;         // ~ tid/40.96
  const int dA = tid - sA * 40;
  const bool xth = (tid < 160);
  const float* xp = X + (size_t)(s0 + sA) * (TT * DD) + dA;

  float xr[4];
  if (xth) {
    sm.s.Abuf[0][sA * AROW + dA] = f2bf(xp[0]);   // x_0
    #pragma unroll
    for (int j = 1; j <= 4; ++j) xr[j & 3] = xp[j * DD];  // x_1..x_4 (TT>=5)
  }
  __syncthreads();   // x_0 visible; ring loads above drain here (init only)

  float cst = 0.f, hf = 0.f;

  for (int t = 0; t < ml; ++t) {
    const int p = t & 1;
    const ushort* Ab = &sm.s.Abuf[p][0];
    short8 Af[6];
    #pragma unroll
    for (int kt = 0; kt < 6; ++kt)
      Af[kt] = *reinterpret_cast<const short8*>(
          &Ab[(lane & 15) * AROW + kt * 32 + (lane >> 4) * 8]);

    f32x4 zero4 = {0.f, 0.f, 0.f, 0.f};
    f32x4 acc[4] = {zero4, zero4, zero4, zero4};
    #pragma unroll
    for (int kt = 0; kt < 6; ++kt) {
      #pragma unroll
      for (int nt = 0; nt < 4; ++nt)
        acc[nt] = __builtin_amdgcn_mfma_f32_16x16x32_bf16(Af[kt], Bf[kt][nt], acc[nt], 0, 0, 0);
    }

    // z slice (wave-private): rows 0..3 held by lanes 0..15 (q=0), regs r
    if (lane < 16) {
      #pragma unroll
      for (int nt = 0; nt < 4; ++nt) {
        #pragma unroll
        for (int r = 0; r < 4; ++r)
          sm.s.zbuf[r * ZROW + wv * 64 + nt * 16 + lane] = acc[nt][r];
      }
    }
    asm volatile("s_waitcnt lgkmcnt(0)" ::: "memory");  // wave-local order

    f32x4 z = *reinterpret_cast<const f32x4*>(
        &sm.s.zbuf[ps * ZROW + wv * 64 + 4 * (lane & 15)]);
    float nc = cst * sigm(z[2] + bfp) + sigm(z[0] + bi) * tanh_f(z[1] + bj);
    float nh = tanh_f(nc) * sigm(z[3] + bo);
    cst = nc;
    if (t == mylen - 1) hf = nh;

    ushort* An = &sm.s.Abuf[1 - p][0];
    ushort hh = f2bf(nh);
    An[ps * AROW + 64 + u] = hh;
    An[ps * AROW + 128 + u] = f2bf(nh - bf2f(hh));
    if (xth) {
      An[sA * AROW + dA] = f2bf(xr[(t + 1) & 3]);
      float nv = 0.f;
      if (t + 5 < TT) nv = xp[(t + 5) * DD];    // stays in flight ~4 steps
      xr[(t + 1) & 3] = nv;
    }
    block_sync_lds();
  }

  // ---- fused head: dense1 + BN + ReLU -> dense2 -> softmax ----
  sm.h.hbuf[ps * 64 + u] = hf;
  block_sync_lds();

  {
    const int j = tid & 127, sp = tid >> 7;   // samples sp, sp+2
    float a0 = b1[j], a1 = a0;
    for (int k = 0; k < 64; ++k) {
      float w = W1[k * 128 + j];
      a0 = fmaf(sm.h.hbuf[sp * 64 + k], w, a0);
      a1 = fmaf(sm.h.hbuf[(sp + 2) * 64 + k], w, a1);
    }
    const float ga = gamma[j], be = beta[j], mm = mmean[j];
    const float iv = rsqrtf(mvar[j] + 1e-3f);
    a0 = fmaxf(a0, 0.f); a1 = fmaxf(a1, 0.f);
    sm.h.d1t[j * 4 + sp]     = ga * (a0 - mm) * iv + be;
    sm.h.d1t[j * 4 + sp + 2] = ga * (a1 - mm) * iv + be;
  }
  block_sync_lds();

  {
    const int cA = tid * 2;
    float ax[4], ay[4];
    const float bA = b2[cA], bB = b2[cA + 1];
    #pragma unroll
    for (int s = 0; s < 4; ++s) { ax[s] = bA; ay[s] = bB; }
    #pragma unroll 4
    for (int k = 0; k < 128; ++k) {
      const float2 w = *reinterpret_cast<const float2*>(&W2[k * 512 + cA]);
      const f32x4 d = *reinterpret_cast<const f32x4*>(&sm.h.d1t[k * 4]);
      #pragma unroll
      for (int s = 0; s < 4; ++s) {
        ax[s] = fmaf(d[s], w.x, ax[s]);
        ay[s] = fmaf(d[s], w.y, ay[s]);
      }
    }
    #pragma unroll
    for (int s = 0; s < 4; ++s) {
      float2 lw = make_float2(ax[s], ay[s]);
      *reinterpret_cast<float2*>(&sm.h.lg[s * 512 + cA]) = lw;
    }
  }
  block_sync_lds();

  {  // softmax: wave wv handles sample wv
    float v[8];
    float m = -3.4e38f;
    #pragma unroll
    for (int i = 0; i < 8; ++i) {
      v[i] = sm.h.lg[wv * 512 + lane + 64 * i];
      m = fmaxf(m, v[i]);
    }
    #pragma unroll
    for (int off = 1; off < 64; off <<= 1) m = fmaxf(m, __shfl_xor(m, off));
    float sum = 0.f;
    #pragma unroll
    for (int i = 0; i < 8; ++i) { v[i] = __expf(v[i] - m); sum += v[i]; }
    #pragma unroll
    for (int off = 1; off < 64; off <<= 1) sum += __shfl_xor(sum, off);
    const float inv = __builtin_amdgcn_rcpf(sum);
    #pragma unroll
    for (int i = 0; i < 8; ++i)
      out[(size_t)(s0 + wv) * 512 + lane + 64 * i] = v[i] * inv;
  }
}

extern "C" void kernel_launch(void* const* d_in, const int* in_sizes, int n_in,
                              void* d_out, int out_size, void* d_ws, size_t ws_size,
                              hipStream_t stream) {
  const float* X      = (const float*)d_in[0];
  const int*   seqlen = (const int*)d_in[1];
  const float* Wk     = (const float*)d_in[2];
  const float* bias   = (const float*)d_in[3];
  const float* W1     = (const float*)d_in[4];
  const float* b1     = (const float*)d_in[5];
  const float* gam    = (const float*)d_in[6];
  const float* bet    = (const float*)d_in[7];
  const float* mmean  = (const float*)d_in[8];
  const float* mvar   = (const float*)d_in[9];
  const float* W2     = (const float*)d_in[10];
  const float* b2     = (const float*)d_in[11];
  float* out = (float*)d_out;

  lstm_fused_kernel<<<dim3(512), dim3(256), 0, stream>>>(
      X, seqlen, Wk, bias, W1, b1, gam, bet, mmean, mvar, W2, b2, out);
}